// Round 1
// baseline (26212.146 us; speedup 1.0000x reference)
//
#include <hip/hip_runtime.h>
#include <hip/hip_bf16.h>
#include <hip/hip_cooperative_groups.h>

namespace cg = cooperative_groups;

#define Bv 64
#define Tv 512
#define Iv 1024
#define Hv 1024
#define G4v 4096

typedef __attribute__((ext_vector_type(8))) short bf16x8;
typedef __attribute__((ext_vector_type(4))) float f32x4;

__device__ __forceinline__ float sigmoid_f(float v) { return 1.f / (1.f + __expf(-v)); }
// tanh via exp, saturates correctly at +/-inf (no inf/inf NaN)
__device__ __forceinline__ float tanh_f(float v) { return 1.f - 2.f / (__expf(2.f * v) + 1.f); }

// ---------------- prep: weights -> bf16, bias sum, zero h ping-pong ----------------
__global__ void prep(const float* __restrict__ w_ih, const float* __restrict__ w_hh,
                     const float* __restrict__ b_ih, const float* __restrict__ b_hh,
                     __hip_bfloat16* __restrict__ wbih, __hip_bfloat16* __restrict__ wbhh,
                     float* __restrict__ bias, __hip_bfloat16* __restrict__ hbuf) {
  unsigned i = blockIdx.x * 256u + threadIdx.x;   // grid covers exactly 4096*1024
  wbih[i] = __float2bfloat16(w_ih[i]);
  wbhh[i] = __float2bfloat16(w_hh[i]);
  if (i < (unsigned)G4v) bias[i] = b_ih[i] + b_hh[i];
  if (i < 2u * Bv * Hv) hbuf[i] = __float2bfloat16(0.f);
}

// ---------------- persistent cooperative LSTM ----------------
// grid = 128 blocks x 256 threads. blocks 0..63: recurrent (h) WGs, each owns 16 h-columns
// (= 64 gate columns). blocks 64..127: producer (x) WGs computing xg for step t+1.
// LDS: [0,128K): weight slice wslice[n][k] bf16 (n=0..63 local gate col, k=0..1023),
//                XOR-swizzled byte ^= (n&7)<<4  (conflict-free ds_read_b128).
//      [128K, +16640): gates exchange buffer f32 [64][65] (h-WGs only).
__global__ void __launch_bounds__(256, 1) lstm_main(
    const float* __restrict__ x,
    const __hip_bfloat16* __restrict__ wbih,
    const __hip_bfloat16* __restrict__ wbhh,
    const float* __restrict__ bias,
    __hip_bfloat16* __restrict__ hbuf,   // [2][B][H] bf16 ping-pong
    float* __restrict__ xg,              // [2][B][4H] f32 ping-pong
    float* __restrict__ out)             // B*T*H + B*H + B*H
{
  extern __shared__ char lds[];
  float* gbuf = (float*)(lds + 131072);

  cg::grid_group grid = cg::this_grid();

  const int bid  = blockIdx.x;
  const bool is_h = (bid < 64);
  const int wg   = is_h ? bid : (bid - 64);
  const int tid  = threadIdx.x;
  const int lane = tid & 63;
  const int wave = tid >> 6;
  const int wm   = wave >> 1;        // 0..1 : 32-row half
  const int wn   = wave & 1;         // 0..1 : 32-col half
  const int lrow = lane & 15;        // A row / B,D col within fragment
  const int lkg  = lane >> 4;        // 0..3
  const int lk   = lkg * 8;          // k offset within 32

  // ---- stage this WG's weight slice into LDS (once, swizzled) ----
  {
    const __hip_bfloat16* wsrc = is_h ? wbhh : wbih;
    for (int c = tid; c < 8192; c += 256) {       // 8192 chunks of 16B = 128KB
      int n   = c >> 7;                           // local col 0..63
      int k16 = c & 127;                          // 16B chunk in k
      int gc  = ((n >> 4) << 10) + (wg << 4) + (n & 15);   // global gate row of w
      uint4 v = *(const uint4*)(wsrc + ((size_t)gc << 10) + (k16 << 3));
      unsigned byt = (unsigned)((n << 11) + (k16 << 4)) ^ ((unsigned)(n & 7) << 4);
      *(uint4*)(&lds[byt]) = v;
    }
  }
  __syncthreads();

  // ---- persistent per-thread elementwise state (h-WGs) ----
  const int eb  = tid >> 2;            // batch row 0..63
  const int ec0 = (tid & 3) << 2;      // h-col offset base within 16
  float c_state[4] = {0.f, 0.f, 0.f, 0.f};
  float biasv[16];
  if (is_h) {
    for (int g = 0; g < 4; ++g)
      for (int j = 0; j < 4; ++j)
        biasv[g * 4 + j] = bias[(g << 10) + (wg << 4) + ec0 + j];
  }

  // ---- x-side GEMM: xg[t_x & 1] = x_t  @ w_ih_slice^T ----
  auto x_gemm = [&](int t_x) {
    f32x4 acc[2][2];
    for (int mf = 0; mf < 2; ++mf)
      for (int nf = 0; nf < 2; ++nf) acc[mf][nf] = f32x4{0.f, 0.f, 0.f, 0.f};
    const float* xa0 = x + (size_t)((wm << 5) + lrow) * (Tv * Iv) + ((size_t)t_x << 10) + lk;
    const float* xa1 = xa0 + (size_t)16 * (Tv * Iv);
    for (int ks = 0; ks < 32; ++ks) {
      int k0 = (ks << 5) + lk;
      bf16x8 a[2];
      {
        const float4* p0 = (const float4*)(xa0 + (ks << 5));
        float4 f0 = p0[0], f1 = p0[1];
        union { __hip_bfloat16 e[8]; bf16x8 v; } u;
        u.e[0] = __float2bfloat16(f0.x); u.e[1] = __float2bfloat16(f0.y);
        u.e[2] = __float2bfloat16(f0.z); u.e[3] = __float2bfloat16(f0.w);
        u.e[4] = __float2bfloat16(f1.x); u.e[5] = __float2bfloat16(f1.y);
        u.e[6] = __float2bfloat16(f1.z); u.e[7] = __float2bfloat16(f1.w);
        a[0] = u.v;
        const float4* p1 = (const float4*)(xa1 + (ks << 5));
        float4 g0 = p1[0], g1 = p1[1];
        union { __hip_bfloat16 e[8]; bf16x8 v; } w;
        w.e[0] = __float2bfloat16(g0.x); w.e[1] = __float2bfloat16(g0.y);
        w.e[2] = __float2bfloat16(g0.z); w.e[3] = __float2bfloat16(g0.w);
        w.e[4] = __float2bfloat16(g1.x); w.e[5] = __float2bfloat16(g1.y);
        w.e[6] = __float2bfloat16(g1.z); w.e[7] = __float2bfloat16(g1.w);
        a[1] = w.v;
      }
      bf16x8 b[2];
      for (int nf = 0; nf < 2; ++nf) {
        int n = (wn << 5) + (nf << 4) + lrow;
        unsigned byt = (unsigned)((n << 11) + (k0 << 1)) ^ ((unsigned)(n & 7) << 4);
        b[nf] = *(const bf16x8*)(&lds[byt]);
      }
      for (int mf = 0; mf < 2; ++mf)
        for (int nf = 0; nf < 2; ++nf)
          acc[mf][nf] = __builtin_amdgcn_mfma_f32_16x16x32_bf16(a[mf], b[nf], acc[mf][nf], 0, 0, 0);
    }
    float* dst = xg + (size_t)(t_x & 1) * (Bv * G4v);
    for (int mf = 0; mf < 2; ++mf)
      for (int nf = 0; nf < 2; ++nf) {
        int nl = (wn << 5) + (nf << 4) + lrow;
        int gc = ((nl >> 4) << 10) + (wg << 4) + (nl & 15);
        int rowb = (wm << 5) + (mf << 4) + (lkg << 2);
        for (int r = 0; r < 4; ++r)
          dst[(size_t)(rowb + r) * G4v + gc] = acc[mf][nf][r];
      }
  };

  // ---- h-side: GEMM + gates + elementwise + h/out writes ----
  auto h_step = [&](int t) {
    const __hip_bfloat16* hp = hbuf + (size_t)((t + 1) & 1) * (Bv * Hv);
    f32x4 acc[2][2];
    for (int mf = 0; mf < 2; ++mf)
      for (int nf = 0; nf < 2; ++nf) acc[mf][nf] = f32x4{0.f, 0.f, 0.f, 0.f};
    const __hip_bfloat16* ha0 = hp + ((size_t)((wm << 5) + lrow) << 10) + lk;
    const __hip_bfloat16* ha1 = ha0 + ((size_t)16 << 10);
    for (int ks = 0; ks < 32; ++ks) {
      int k0 = (ks << 5) + lk;
      bf16x8 a0 = *(const bf16x8*)(ha0 + (ks << 5));
      bf16x8 a1 = *(const bf16x8*)(ha1 + (ks << 5));
      bf16x8 b[2];
      for (int nf = 0; nf < 2; ++nf) {
        int n = (wn << 5) + (nf << 4) + lrow;
        unsigned byt = (unsigned)((n << 11) + (k0 << 1)) ^ ((unsigned)(n & 7) << 4);
        b[nf] = *(const bf16x8*)(&lds[byt]);
      }
      acc[0][0] = __builtin_amdgcn_mfma_f32_16x16x32_bf16(a0, b[0], acc[0][0], 0, 0, 0);
      acc[0][1] = __builtin_amdgcn_mfma_f32_16x16x32_bf16(a0, b[1], acc[0][1], 0, 0, 0);
      acc[1][0] = __builtin_amdgcn_mfma_f32_16x16x32_bf16(a1, b[0], acc[1][0], 0, 0, 0);
      acc[1][1] = __builtin_amdgcn_mfma_f32_16x16x32_bf16(a1, b[1], acc[1][1], 0, 0, 0);
    }
    // exchange gates through LDS so each thread owns all 4 gates of its (b, hcol)
    for (int mf = 0; mf < 2; ++mf)
      for (int nf = 0; nf < 2; ++nf) {
        int col  = (wn << 5) + (nf << 4) + lrow;
        int rowb = (wm << 5) + (mf << 4) + (lkg << 2);
        for (int r = 0; r < 4; ++r)
          gbuf[(rowb + r) * 65 + col] = acc[mf][nf][r];
      }
    __syncthreads();
    const float* xgs = xg + (size_t)(t & 1) * (Bv * G4v);
    float hv[4];
    for (int j = 0; j < 4; ++j) {
      int cc = ec0 + j;
      int colbase = (wg << 4) + cc;
      float g0 = gbuf[eb * 65 +      cc] + xgs[(size_t)eb * G4v +        colbase] + biasv[0 + j];
      float g1 = gbuf[eb * 65 + 16 + cc] + xgs[(size_t)eb * G4v + 1024 + colbase] + biasv[4 + j];
      float g2 = gbuf[eb * 65 + 32 + cc] + xgs[(size_t)eb * G4v + 2048 + colbase] + biasv[8 + j];
      float g3 = gbuf[eb * 65 + 48 + cc] + xgs[(size_t)eb * G4v + 3072 + colbase] + biasv[12 + j];
      float ig = sigmoid_f(g0);
      float fg = sigmoid_f(g1);
      float gg = tanh_f(g2);
      float og = sigmoid_f(g3);
      float cv = fg * c_state[j] + ig * gg;
      c_state[j] = cv;
      hv[j] = og * tanh_f(cv);
    }
    __hip_bfloat16* hw = hbuf + (size_t)(t & 1) * (Bv * Hv) + ((size_t)eb << 10) + (wg << 4) + ec0;
    float* ow = out + (size_t)eb * (Tv * Hv) + ((size_t)t << 10) + (wg << 4) + ec0;
    for (int j = 0; j < 4; ++j) {
      hw[j] = __float2bfloat16(hv[j]);
      ow[j] = hv[j];
    }
    if (t == Tv - 1) {
      float* hn = out + (size_t)Bv * Tv * Hv + ((size_t)eb << 10) + (wg << 4) + ec0;
      float* cn = hn + (size_t)Bv * Hv;
      for (int j = 0; j < 4; ++j) { hn[j] = hv[j]; cn[j] = c_state[j]; }
    }
  };

  // ---- main sequence ----
  if (!is_h) x_gemm(0);
  __threadfence();
  grid.sync();
  for (int t = 0; t < Tv; ++t) {
    if (is_h)             h_step(t);
    else if (t + 1 < Tv)  x_gemm(t + 1);
    __threadfence();
    grid.sync();
  }
}

// ---------------- host launch ----------------
extern "C" void kernel_launch(void* const* d_in, const int* in_sizes, int n_in,
                              void* d_out, int out_size, void* d_ws, size_t ws_size,
                              hipStream_t stream) {
  const float* x    = (const float*)d_in[0];
  const float* w_ih = (const float*)d_in[1];
  const float* b_ih = (const float*)d_in[2];
  const float* w_hh = (const float*)d_in[3];
  const float* b_hh = (const float*)d_in[4];
  float* out = (float*)d_out;

  char* ws = (char*)d_ws;
  __hip_bfloat16* wbih = (__hip_bfloat16*)(ws);                              // 8 MB
  __hip_bfloat16* wbhh = (__hip_bfloat16*)(ws + (size_t)(8u << 20));         // 8 MB
  float*          bias = (float*)(ws + (size_t)(16u << 20));                 // 16 KB
  __hip_bfloat16* hbuf = (__hip_bfloat16*)(ws + (size_t)(16u << 20) + 65536);// 256 KB
  float*          xg   = (float*)(ws + (size_t)(16u << 20) + 65536 + 262144);// 2 MB

  hipLaunchKernelGGL(prep, dim3(16384), dim3(256), 0, stream,
                     w_ih, w_hh, b_ih, b_hh, wbih, wbhh, bias, hbuf);

  const unsigned ldsBytes = 131072u + 64u * 65u * 4u;  // 147712
  hipFuncSetAttribute((const void*)lstm_main,
                      hipFuncAttributeMaxDynamicSharedMemorySize, (int)ldsBytes);

  const float* xA = x;
  const __hip_bfloat16* wbihA = wbih;
  const __hip_bfloat16* wbhhA = wbhh;
  const float* biasA = bias;
  __hip_bfloat16* hbufA = hbuf;
  float* xgA = xg;
  float* outA = out;
  void* args[7] = {(void*)&xA, (void*)&wbihA, (void*)&wbhhA, (void*)&biasA,
                   (void*)&hbufA, (void*)&xgA, (void*)&outA};
  hipLaunchCooperativeKernel((const void*)lstm_main, dim3(128), dim3(256),
                             args, ldsBytes, stream);
}

// Round 2
// 13659.006 us; speedup vs baseline: 1.9190x; 1.9190x over previous
//
#include <hip/hip_runtime.h>
#include <hip/hip_bf16.h>

#define Bv 64
#define Tv 512
#define Iv 1024
#define Hv 1024
#define G4v 4096
#define NBLK 128

typedef __attribute__((ext_vector_type(8))) short bf16x8;
typedef __attribute__((ext_vector_type(4))) float f32x4;

__device__ __forceinline__ float sigmoid_f(float v) { return 1.f / (1.f + __expf(-v)); }
// tanh via exp, saturates correctly at +/-inf (no inf/inf NaN)
__device__ __forceinline__ float tanh_f(float v) { return 1.f - 2.f / (__expf(2.f * v) + 1.f); }

// Custom grid barrier: monotonic epoch counter in global memory.
// Leader does device-scope release-add (flushes this XCD's dirty L2 lines),
// relaxed-agent polls (no repeated invalidates), one acquire fence on exit.
__device__ __forceinline__ void gbar(unsigned* bar, unsigned target) {
  __syncthreads();                       // all block threads' work issued/complete
  if (threadIdx.x == 0) {
    __hip_atomic_fetch_add(bar, 1u, __ATOMIC_RELEASE, __HIP_MEMORY_SCOPE_AGENT);
    while (__hip_atomic_load(bar, __ATOMIC_RELAXED, __HIP_MEMORY_SCOPE_AGENT) < target)
      __builtin_amdgcn_s_sleep(1);
    __builtin_amdgcn_fence(__ATOMIC_ACQUIRE, "agent");   // inv L1 + XCD L2
  }
  __syncthreads();
}

// ---------------- prep: weights -> bf16, bias sum, zero h ping-pong, zero barrier ----------------
__global__ void prep(const float* __restrict__ w_ih, const float* __restrict__ w_hh,
                     const float* __restrict__ b_ih, const float* __restrict__ b_hh,
                     __hip_bfloat16* __restrict__ wbih, __hip_bfloat16* __restrict__ wbhh,
                     float* __restrict__ bias, __hip_bfloat16* __restrict__ hbuf,
                     unsigned* __restrict__ bar) {
  unsigned i = blockIdx.x * 256u + threadIdx.x;   // grid covers exactly 4096*1024
  wbih[i] = __float2bfloat16(w_ih[i]);
  wbhh[i] = __float2bfloat16(w_hh[i]);
  if (i < (unsigned)G4v) bias[i] = b_ih[i] + b_hh[i];
  if (i < 2u * Bv * Hv) hbuf[i] = __float2bfloat16(0.f);
  if (i == 0) *bar = 0u;
}

// ---------------- persistent cooperative LSTM ----------------
// grid = 128 blocks x 256 threads. blocks 0..63: recurrent (h) WGs, each owns 16 h-columns
// (= 64 gate columns). blocks 64..127: producer (x) WGs computing xg for step t+1.
// LDS: [0,128K): weight slice wslice[n][k] bf16 (n=0..63 local gate col, k=0..1023),
//                XOR-swizzled byte ^= (n&7)<<4  (conflict-free ds_read_b128).
//      [128K, +16640): gates exchange buffer f32 [64][65] (h-WGs only).
__global__ void __launch_bounds__(256, 1) lstm_main(
    const float* __restrict__ x,
    const __hip_bfloat16* __restrict__ wbih,
    const __hip_bfloat16* __restrict__ wbhh,
    const float* __restrict__ bias,
    __hip_bfloat16* __restrict__ hbuf,   // [2][B][H] bf16 ping-pong
    float* __restrict__ xg,              // [2][B][4H] f32 ping-pong
    float* __restrict__ out,             // B*T*H + B*H + B*H
    unsigned* __restrict__ bar)
{
  extern __shared__ char lds[];
  float* gbuf = (float*)(lds + 131072);

  const int bid  = blockIdx.x;
  const bool is_h = (bid < 64);
  const int wg   = is_h ? bid : (bid - 64);
  const int tid  = threadIdx.x;
  const int lane = tid & 63;
  const int wave = tid >> 6;
  const int wm   = wave >> 1;        // 0..1 : 32-row half
  const int wn   = wave & 1;         // 0..1 : 32-col half
  const int lrow = lane & 15;        // A row / B,D col within fragment
  const int lkg  = lane >> 4;        // 0..3
  const int lk   = lkg * 8;          // k offset within 32

  // ---- stage this WG's weight slice into LDS (once, swizzled) ----
  {
    const __hip_bfloat16* wsrc = is_h ? wbhh : wbih;
    for (int c = tid; c < 8192; c += 256) {       // 8192 chunks of 16B = 128KB
      int n   = c >> 7;                           // local col 0..63
      int k16 = c & 127;                          // 16B chunk in k
      int gc  = ((n >> 4) << 10) + (wg << 4) + (n & 15);   // global gate row of w
      uint4 v = *(const uint4*)(wsrc + ((size_t)gc << 10) + (k16 << 3));
      unsigned byt = (unsigned)((n << 11) + (k16 << 4)) ^ ((unsigned)(n & 7) << 4);
      *(uint4*)(&lds[byt]) = v;
    }
  }
  __syncthreads();

  // ---- persistent per-thread elementwise state (h-WGs) ----
  const int eb  = tid >> 2;            // batch row 0..63
  const int ec0 = (tid & 3) << 2;      // h-col offset base within 16
  float c_state[4] = {0.f, 0.f, 0.f, 0.f};
  float biasv[16];
  if (is_h) {
    for (int g = 0; g < 4; ++g)
      for (int j = 0; j < 4; ++j)
        biasv[g * 4 + j] = bias[(g << 10) + (wg << 4) + ec0 + j];
  }

  // ---- x-side GEMM: xg[t_x & 1] = x_t  @ w_ih_slice^T ----
  auto x_gemm = [&](int t_x) {
    f32x4 acc[2][2];
    for (int mf = 0; mf < 2; ++mf)
      for (int nf = 0; nf < 2; ++nf) acc[mf][nf] = f32x4{0.f, 0.f, 0.f, 0.f};
    const float* xa0 = x + (size_t)((wm << 5) + lrow) * (Tv * Iv) + ((size_t)t_x << 10) + lk;
    const float* xa1 = xa0 + (size_t)16 * (Tv * Iv);
    for (int ks = 0; ks < 32; ++ks) {
      int k0 = (ks << 5) + lk;
      bf16x8 a[2];
      {
        const float4* p0 = (const float4*)(xa0 + (ks << 5));
        float4 f0 = p0[0], f1 = p0[1];
        union { __hip_bfloat16 e[8]; bf16x8 v; } u;
        u.e[0] = __float2bfloat16(f0.x); u.e[1] = __float2bfloat16(f0.y);
        u.e[2] = __float2bfloat16(f0.z); u.e[3] = __float2bfloat16(f0.w);
        u.e[4] = __float2bfloat16(f1.x); u.e[5] = __float2bfloat16(f1.y);
        u.e[6] = __float2bfloat16(f1.z); u.e[7] = __float2bfloat16(f1.w);
        a[0] = u.v;
        const float4* p1 = (const float4*)(xa1 + (ks << 5));
        float4 g0 = p1[0], g1 = p1[1];
        union { __hip_bfloat16 e[8]; bf16x8 v; } w;
        w.e[0] = __float2bfloat16(g0.x); w.e[1] = __float2bfloat16(g0.y);
        w.e[2] = __float2bfloat16(g0.z); w.e[3] = __float2bfloat16(g0.w);
        w.e[4] = __float2bfloat16(g1.x); w.e[5] = __float2bfloat16(g1.y);
        w.e[6] = __float2bfloat16(g1.z); w.e[7] = __float2bfloat16(g1.w);
        a[1] = w.v;
      }
      bf16x8 b[2];
      for (int nf = 0; nf < 2; ++nf) {
        int n = (wn << 5) + (nf << 4) + lrow;
        unsigned byt = (unsigned)((n << 11) + (k0 << 1)) ^ ((unsigned)(n & 7) << 4);
        b[nf] = *(const bf16x8*)(&lds[byt]);
      }
      for (int mf = 0; mf < 2; ++mf)
        for (int nf = 0; nf < 2; ++nf)
          acc[mf][nf] = __builtin_amdgcn_mfma_f32_16x16x32_bf16(a[mf], b[nf], acc[mf][nf], 0, 0, 0);
    }
    float* dst = xg + (size_t)(t_x & 1) * (Bv * G4v);
    for (int mf = 0; mf < 2; ++mf)
      for (int nf = 0; nf < 2; ++nf) {
        int nl = (wn << 5) + (nf << 4) + lrow;
        int gc = ((nl >> 4) << 10) + (wg << 4) + (nl & 15);
        int rowb = (wm << 5) + (mf << 4) + (lkg << 2);
        for (int r = 0; r < 4; ++r)
          dst[(size_t)(rowb + r) * G4v + gc] = acc[mf][nf][r];
      }
  };

  // ---- h-side: GEMM + gates + elementwise + h/out writes ----
  auto h_step = [&](int t) {
    // prefetch this thread's xg slice early; loads overlap the MFMA loop
    const float* xgs = xg + (size_t)(t & 1) * (Bv * G4v);
    float xgv[16];
    for (int g = 0; g < 4; ++g) {
      const float4 v = *(const float4*)(xgs + (size_t)eb * G4v + (g << 10) + (wg << 4) + ec0);
      xgv[g * 4 + 0] = v.x; xgv[g * 4 + 1] = v.y; xgv[g * 4 + 2] = v.z; xgv[g * 4 + 3] = v.w;
    }
    const __hip_bfloat16* hp = hbuf + (size_t)((t + 1) & 1) * (Bv * Hv);
    f32x4 acc[2][2];
    for (int mf = 0; mf < 2; ++mf)
      for (int nf = 0; nf < 2; ++nf) acc[mf][nf] = f32x4{0.f, 0.f, 0.f, 0.f};
    const __hip_bfloat16* ha0 = hp + ((size_t)((wm << 5) + lrow) << 10) + lk;
    const __hip_bfloat16* ha1 = ha0 + ((size_t)16 << 10);
    for (int ks = 0; ks < 32; ++ks) {
      int k0 = (ks << 5) + lk;
      bf16x8 a0 = *(const bf16x8*)(ha0 + (ks << 5));
      bf16x8 a1 = *(const bf16x8*)(ha1 + (ks << 5));
      bf16x8 b[2];
      for (int nf = 0; nf < 2; ++nf) {
        int n = (wn << 5) + (nf << 4) + lrow;
        unsigned byt = (unsigned)((n << 11) + (k0 << 1)) ^ ((unsigned)(n & 7) << 4);
        b[nf] = *(const bf16x8*)(&lds[byt]);
      }
      acc[0][0] = __builtin_amdgcn_mfma_f32_16x16x32_bf16(a0, b[0], acc[0][0], 0, 0, 0);
      acc[0][1] = __builtin_amdgcn_mfma_f32_16x16x32_bf16(a0, b[1], acc[0][1], 0, 0, 0);
      acc[1][0] = __builtin_amdgcn_mfma_f32_16x16x32_bf16(a1, b[0], acc[1][0], 0, 0, 0);
      acc[1][1] = __builtin_amdgcn_mfma_f32_16x16x32_bf16(a1, b[1], acc[1][1], 0, 0, 0);
    }
    // exchange gates through LDS so each thread owns all 4 gates of its (b, hcol)
    for (int mf = 0; mf < 2; ++mf)
      for (int nf = 0; nf < 2; ++nf) {
        int col  = (wn << 5) + (nf << 4) + lrow;
        int rowb = (wm << 5) + (mf << 4) + (lkg << 2);
        for (int r = 0; r < 4; ++r)
          gbuf[(rowb + r) * 65 + col] = acc[mf][nf][r];
      }
    __syncthreads();
    float hv[4];
    for (int j = 0; j < 4; ++j) {
      int cc = ec0 + j;
      float g0 = gbuf[eb * 65 +      cc] + xgv[0 + j]  + biasv[0 + j];
      float g1 = gbuf[eb * 65 + 16 + cc] + xgv[4 + j]  + biasv[4 + j];
      float g2 = gbuf[eb * 65 + 32 + cc] + xgv[8 + j]  + biasv[8 + j];
      float g3 = gbuf[eb * 65 + 48 + cc] + xgv[12 + j] + biasv[12 + j];
      float ig = sigmoid_f(g0);
      float fg = sigmoid_f(g1);
      float gg = tanh_f(g2);
      float og = sigmoid_f(g3);
      float cv = fg * c_state[j] + ig * gg;
      c_state[j] = cv;
      hv[j] = og * tanh_f(cv);
    }
    __hip_bfloat16* hw = hbuf + (size_t)(t & 1) * (Bv * Hv) + ((size_t)eb << 10) + (wg << 4) + ec0;
    float* ow = out + (size_t)eb * (Tv * Hv) + ((size_t)t << 10) + (wg << 4) + ec0;
    for (int j = 0; j < 4; ++j) {
      hw[j] = __float2bfloat16(hv[j]);
      ow[j] = hv[j];
    }
    if (t == Tv - 1) {
      float* hn = out + (size_t)Bv * Tv * Hv + ((size_t)eb << 10) + (wg << 4) + ec0;
      float* cn = hn + (size_t)Bv * Hv;
      for (int j = 0; j < 4; ++j) { hn[j] = hv[j]; cn[j] = c_state[j]; }
    }
  };

  // ---- main sequence ----
  if (!is_h) x_gemm(0);
  unsigned ep = 1;
  gbar(bar, NBLK * ep); ++ep;
  for (int t = 0; t < Tv; ++t) {
    if (is_h)             h_step(t);
    else if (t + 1 < Tv)  x_gemm(t + 1);
    if (t + 1 < Tv) { gbar(bar, NBLK * ep); ++ep; }
  }
}

// ---------------- host launch ----------------
extern "C" void kernel_launch(void* const* d_in, const int* in_sizes, int n_in,
                              void* d_out, int out_size, void* d_ws, size_t ws_size,
                              hipStream_t stream) {
  const float* x    = (const float*)d_in[0];
  const float* w_ih = (const float*)d_in[1];
  const float* b_ih = (const float*)d_in[2];
  const float* w_hh = (const float*)d_in[3];
  const float* b_hh = (const float*)d_in[4];
  float* out = (float*)d_out;

  char* ws = (char*)d_ws;
  __hip_bfloat16* wbih = (__hip_bfloat16*)(ws);                              // 8 MB
  __hip_bfloat16* wbhh = (__hip_bfloat16*)(ws + (size_t)(8u << 20));         // 8 MB
  float*          bias = (float*)(ws + (size_t)(16u << 20));                 // 16 KB
  __hip_bfloat16* hbuf = (__hip_bfloat16*)(ws + (size_t)(16u << 20) + 65536);// 256 KB
  float*          xg   = (float*)(ws + (size_t)(16u << 20) + 65536 + 262144);// 2 MB
  unsigned*       bar  = (unsigned*)(ws + (size_t)(20u << 20));              // 64 B

  hipLaunchKernelGGL(prep, dim3(16384), dim3(256), 0, stream,
                     w_ih, w_hh, b_ih, b_hh, wbih, wbhh, bias, hbuf, bar);

  const unsigned ldsBytes = 131072u + 64u * 65u * 4u;  // 147712
  hipFuncSetAttribute((const void*)lstm_main,
                      hipFuncAttributeMaxDynamicSharedMemorySize, (int)ldsBytes);

  const float* xA = x;
  const __hip_bfloat16* wbihA = wbih;
  const __hip_bfloat16* wbhhA = wbhh;
  const float* biasA = bias;
  __hip_bfloat16* hbufA = hbuf;
  float* xgA = xg;
  float* outA = out;
  unsigned* barA = bar;
  void* args[8] = {(void*)&xA, (void*)&wbihA, (void*)&wbhhA, (void*)&biasA,
                   (void*)&hbufA, (void*)&xgA, (void*)&outA, (void*)&barA};
  hipLaunchCooperativeKernel((const void*)lstm_main, dim3(NBLK), dim3(256),
                             args, ldsBytes, stream);
}

// Round 3
// 10344.183 us; speedup vs baseline: 2.5340x; 1.3205x over previous
//
#include <hip/hip_runtime.h>
#include <hip/hip_bf16.h>

#define Bv 64
#define Tv 512
#define Iv 1024
#define Hv 1024
#define G4v 4096
#define NBLK 128
#define FLAG_STRIDE 16   // 64B padding per flag -> no same-line store contention

typedef __attribute__((ext_vector_type(8))) short bf16x8;
typedef __attribute__((ext_vector_type(4))) float f32x4;

__device__ __forceinline__ float sigmoid_f(float v) { return 1.f / (1.f + __expf(-v)); }
// tanh via exp, saturates correctly at +/-inf (no inf/inf NaN)
__device__ __forceinline__ float tanh_f(float v) { return 1.f - 2.f / (__expf(2.f * v) + 1.f); }

// Fence-free grid barrier.
// Preconditions: all cross-block data published with relaxed AGENT-scope atomic
// stores (sc1 -> write-through to LLC, no dirty L2), `out` written nontemporal.
// Protocol: per-wave vmcnt(0) drain -> __syncthreads -> leader stores epoch to
// its own padded flag (relaxed agent) -> wave0 lane-parallel polls all 128
// flags (relaxed agent loads, no RMW) -> one acquire fence (buffer_inv, L2 is
// clean so no writeback walk) -> __syncthreads. Readers then use NORMAL cached
// loads: inv forced a miss, data comes fresh from LLC and stays L2-resident.
__device__ __forceinline__ void flag_barrier(unsigned* flags, int bid, unsigned ep) {
  asm volatile("s_waitcnt vmcnt(0)" ::: "memory");  // this wave's sc1 stores are at LLC
  __syncthreads();                                  // all waves of the block drained
  if (threadIdx.x == 0)
    __hip_atomic_store(&flags[bid * FLAG_STRIDE], ep,
                       __ATOMIC_RELAXED, __HIP_MEMORY_SCOPE_AGENT);
  if (threadIdx.x < 64) {
    const int l = threadIdx.x;
    for (;;) {
      unsigned f0 = __hip_atomic_load(&flags[l * FLAG_STRIDE],
                                      __ATOMIC_RELAXED, __HIP_MEMORY_SCOPE_AGENT);
      unsigned f1 = __hip_atomic_load(&flags[(64 + l) * FLAG_STRIDE],
                                      __ATOMIC_RELAXED, __HIP_MEMORY_SCOPE_AGENT);
      if (__all(f0 >= ep && f1 >= ep)) break;
      __builtin_amdgcn_s_sleep(1);
    }
    __builtin_amdgcn_fence(__ATOMIC_ACQUIRE, "agent");  // buffer_inv: L1+L2 invalidate
  }
  __syncthreads();
}

// ---------------- prep: weights -> bf16, bias sum, zero h ping-pong + flags ----------------
__global__ void prep(const float* __restrict__ w_ih, const float* __restrict__ w_hh,
                     const float* __restrict__ b_ih, const float* __restrict__ b_hh,
                     __hip_bfloat16* __restrict__ wbih, __hip_bfloat16* __restrict__ wbhh,
                     float* __restrict__ bias, __hip_bfloat16* __restrict__ hbuf,
                     unsigned* __restrict__ flags) {
  unsigned i = blockIdx.x * 256u + threadIdx.x;   // grid covers exactly 4096*1024
  wbih[i] = __float2bfloat16(w_ih[i]);
  wbhh[i] = __float2bfloat16(w_hh[i]);
  if (i < (unsigned)G4v) bias[i] = b_ih[i] + b_hh[i];
  if (i < 2u * Bv * Hv) hbuf[i] = __float2bfloat16(0.f);
  if (i < (unsigned)(NBLK * FLAG_STRIDE)) flags[i] = 0u;
}

// ---------------- persistent cooperative LSTM ----------------
// grid = 128 blocks x 256 threads. blocks 0..63: recurrent (h) WGs, each owns 16 h-columns
// (= 64 gate columns). blocks 64..127: producer (x) WGs computing xg for step t+1.
// LDS: [0,128K): weight slice wslice[n][k] bf16, XOR-swizzled byte ^= (n&7)<<4.
//      [128K, +16640): gates exchange buffer f32 [64][65] (h-WGs only).
__global__ void __launch_bounds__(256, 1) lstm_main(
    const float* __restrict__ x,
    const __hip_bfloat16* __restrict__ wbih,
    const __hip_bfloat16* __restrict__ wbhh,
    const float* __restrict__ bias,
    __hip_bfloat16* __restrict__ hbuf,   // [2][B][H] bf16 ping-pong (sc1-published)
    float* __restrict__ xg,              // [2][B][4H] f32 ping-pong (sc1-published)
    float* __restrict__ out,             // B*T*H + B*H + B*H (nontemporal)
    unsigned* __restrict__ flags)
{
  extern __shared__ char lds[];
  float* gbuf = (float*)(lds + 131072);

  const int bid  = blockIdx.x;
  const bool is_h = (bid < 64);
  const int wg   = is_h ? bid : (bid - 64);
  const int tid  = threadIdx.x;
  const int lane = tid & 63;
  const int wave = tid >> 6;
  const int wm   = wave >> 1;        // 0..1 : 32-row half
  const int wn   = wave & 1;         // 0..1 : 32-col half
  const int lrow = lane & 15;        // A row / B,D col within fragment
  const int lkg  = lane >> 4;        // 0..3
  const int lk   = lkg * 8;          // k offset within 32

  // ---- stage this WG's weight slice into LDS (once, swizzled) ----
  {
    const __hip_bfloat16* wsrc = is_h ? wbhh : wbih;
    for (int c = tid; c < 8192; c += 256) {       // 8192 chunks of 16B = 128KB
      int n   = c >> 7;                           // local col 0..63
      int k16 = c & 127;                          // 16B chunk in k
      int gc  = ((n >> 4) << 10) + (wg << 4) + (n & 15);   // global gate row of w
      uint4 v = *(const uint4*)(wsrc + ((size_t)gc << 10) + (k16 << 3));
      unsigned byt = (unsigned)((n << 11) + (k16 << 4)) ^ ((unsigned)(n & 7) << 4);
      *(uint4*)(&lds[byt]) = v;
    }
  }
  __syncthreads();

  // ---- persistent per-thread elementwise state (h-WGs) ----
  const int eb  = tid >> 2;            // batch row 0..63
  const int ec0 = (tid & 3) << 2;      // h-col offset base within 16
  float c_state[4] = {0.f, 0.f, 0.f, 0.f};
  float biasv[16];
  if (is_h) {
    for (int g = 0; g < 4; ++g)
      for (int j = 0; j < 4; ++j)
        biasv[g * 4 + j] = bias[(g << 10) + (wg << 4) + ec0 + j];
  }

  // ---- x-side GEMM: xg[t_x & 1] = x_t @ w_ih_slice^T (sc1 stores) ----
  auto x_gemm = [&](int t_x) {
    f32x4 acc[2][2];
    for (int mf = 0; mf < 2; ++mf)
      for (int nf = 0; nf < 2; ++nf) acc[mf][nf] = f32x4{0.f, 0.f, 0.f, 0.f};
    const float* xa0 = x + (size_t)((wm << 5) + lrow) * (Tv * Iv) + ((size_t)t_x << 10) + lk;
    const float* xa1 = xa0 + (size_t)16 * (Tv * Iv);
    for (int ks = 0; ks < 32; ++ks) {
      int k0 = (ks << 5) + lk;
      bf16x8 a[2];
      {
        const float4* p0 = (const float4*)(xa0 + (ks << 5));
        float4 f0 = p0[0], f1 = p0[1];
        union { __hip_bfloat16 e[8]; bf16x8 v; } u;
        u.e[0] = __float2bfloat16(f0.x); u.e[1] = __float2bfloat16(f0.y);
        u.e[2] = __float2bfloat16(f0.z); u.e[3] = __float2bfloat16(f0.w);
        u.e[4] = __float2bfloat16(f1.x); u.e[5] = __float2bfloat16(f1.y);
        u.e[6] = __float2bfloat16(f1.z); u.e[7] = __float2bfloat16(f1.w);
        a[0] = u.v;
        const float4* p1 = (const float4*)(xa1 + (ks << 5));
        float4 g0 = p1[0], g1 = p1[1];
        union { __hip_bfloat16 e[8]; bf16x8 v; } w;
        w.e[0] = __float2bfloat16(g0.x); w.e[1] = __float2bfloat16(g0.y);
        w.e[2] = __float2bfloat16(g0.z); w.e[3] = __float2bfloat16(g0.w);
        w.e[4] = __float2bfloat16(g1.x); w.e[5] = __float2bfloat16(g1.y);
        w.e[6] = __float2bfloat16(g1.z); w.e[7] = __float2bfloat16(g1.w);
        a[1] = w.v;
      }
      bf16x8 b[2];
      for (int nf = 0; nf < 2; ++nf) {
        int n = (wn << 5) + (nf << 4) + lrow;
        unsigned byt = (unsigned)((n << 11) + (k0 << 1)) ^ ((unsigned)(n & 7) << 4);
        b[nf] = *(const bf16x8*)(&lds[byt]);
      }
      for (int mf = 0; mf < 2; ++mf)
        for (int nf = 0; nf < 2; ++nf)
          acc[mf][nf] = __builtin_amdgcn_mfma_f32_16x16x32_bf16(a[mf], b[nf], acc[mf][nf], 0, 0, 0);
    }
    float* dst = xg + (size_t)(t_x & 1) * (Bv * G4v);
    for (int mf = 0; mf < 2; ++mf)
      for (int nf = 0; nf < 2; ++nf) {
        int nl = (wn << 5) + (nf << 4) + lrow;
        int gc = ((nl >> 4) << 10) + (wg << 4) + (nl & 15);
        int rowb = (wm << 5) + (mf << 4) + (lkg << 2);
        for (int r = 0; r < 4; ++r)
          __hip_atomic_store(&dst[(size_t)(rowb + r) * G4v + gc], acc[mf][nf][r],
                             __ATOMIC_RELAXED, __HIP_MEMORY_SCOPE_AGENT);
      }
  };

  // ---- h-side: GEMM + gates + elementwise + h/out writes ----
  auto h_step = [&](int t) {
    // prefetch this thread's xg slice early (normal cached loads; fresh post-inv)
    const float* xgs = xg + (size_t)(t & 1) * (Bv * G4v);
    float xgv[16];
    for (int g = 0; g < 4; ++g) {
      const float4 v = *(const float4*)(xgs + (size_t)eb * G4v + (g << 10) + (wg << 4) + ec0);
      xgv[g * 4 + 0] = v.x; xgv[g * 4 + 1] = v.y; xgv[g * 4 + 2] = v.z; xgv[g * 4 + 3] = v.w;
    }
    const __hip_bfloat16* hp = hbuf + (size_t)((t + 1) & 1) * (Bv * Hv);
    f32x4 acc[2][2];
    for (int mf = 0; mf < 2; ++mf)
      for (int nf = 0; nf < 2; ++nf) acc[mf][nf] = f32x4{0.f, 0.f, 0.f, 0.f};
    const __hip_bfloat16* ha0 = hp + ((size_t)((wm << 5) + lrow) << 10) + lk;
    const __hip_bfloat16* ha1 = ha0 + ((size_t)16 << 10);
    #pragma unroll 8
    for (int ks = 0; ks < 32; ++ks) {
      int k0 = (ks << 5) + lk;
      bf16x8 a0 = *(const bf16x8*)(ha0 + (ks << 5));
      bf16x8 a1 = *(const bf16x8*)(ha1 + (ks << 5));
      bf16x8 b[2];
      for (int nf = 0; nf < 2; ++nf) {
        int n = (wn << 5) + (nf << 4) + lrow;
        unsigned byt = (unsigned)((n << 11) + (k0 << 1)) ^ ((unsigned)(n & 7) << 4);
        b[nf] = *(const bf16x8*)(&lds[byt]);
      }
      acc[0][0] = __builtin_amdgcn_mfma_f32_16x16x32_bf16(a0, b[0], acc[0][0], 0, 0, 0);
      acc[0][1] = __builtin_amdgcn_mfma_f32_16x16x32_bf16(a0, b[1], acc[0][1], 0, 0, 0);
      acc[1][0] = __builtin_amdgcn_mfma_f32_16x16x32_bf16(a1, b[0], acc[1][0], 0, 0, 0);
      acc[1][1] = __builtin_amdgcn_mfma_f32_16x16x32_bf16(a1, b[1], acc[1][1], 0, 0, 0);
    }
    // exchange gates through LDS so each thread owns all 4 gates of its (b, hcol)
    for (int mf = 0; mf < 2; ++mf)
      for (int nf = 0; nf < 2; ++nf) {
        int col  = (wn << 5) + (nf << 4) + lrow;
        int rowb = (wm << 5) + (mf << 4) + (lkg << 2);
        for (int r = 0; r < 4; ++r)
          gbuf[(rowb + r) * 65 + col] = acc[mf][nf][r];
      }
    __syncthreads();
    float hv[4];
    for (int j = 0; j < 4; ++j) {
      int cc = ec0 + j;
      float g0 = gbuf[eb * 65 +      cc] + xgv[0 + j]  + biasv[0 + j];
      float g1 = gbuf[eb * 65 + 16 + cc] + xgv[4 + j]  + biasv[4 + j];
      float g2 = gbuf[eb * 65 + 32 + cc] + xgv[8 + j]  + biasv[8 + j];
      float g3 = gbuf[eb * 65 + 48 + cc] + xgv[12 + j] + biasv[12 + j];
      float ig = sigmoid_f(g0);
      float fg = sigmoid_f(g1);
      float gg = tanh_f(g2);
      float og = sigmoid_f(g3);
      float cv = fg * c_state[j] + ig * gg;
      c_state[j] = cv;
      hv[j] = og * tanh_f(cv);
    }
    // publish new h slice: 4 bf16 packed -> one 8B relaxed agent store (sc1)
    __hip_bfloat16* hw = hbuf + (size_t)(t & 1) * (Bv * Hv) + ((size_t)eb << 10) + (wg << 4) + ec0;
    union { __hip_bfloat16 h[4]; unsigned long long q; } hu;
    for (int j = 0; j < 4; ++j) hu.h[j] = __float2bfloat16(hv[j]);
    __hip_atomic_store((unsigned long long*)hw, hu.q,
                       __ATOMIC_RELAXED, __HIP_MEMORY_SCOPE_AGENT);
    // out is never re-read: nontemporal 16B store, keeps L2 clean
    float* ow = out + (size_t)eb * (Tv * Hv) + ((size_t)t << 10) + (wg << 4) + ec0;
    f32x4 ov = {hv[0], hv[1], hv[2], hv[3]};
    __builtin_nontemporal_store(ov, (f32x4*)ow);
    if (t == Tv - 1) {
      float* hn = out + (size_t)Bv * Tv * Hv + ((size_t)eb << 10) + (wg << 4) + ec0;
      float* cn = hn + (size_t)Bv * Hv;
      for (int j = 0; j < 4; ++j) { hn[j] = hv[j]; cn[j] = c_state[j]; }
    }
  };

  // ---- main sequence ----
  if (!is_h) x_gemm(0);
  unsigned ep = 1;
  flag_barrier(flags, bid, ep); ++ep;
  for (int t = 0; t < Tv; ++t) {
    if (is_h)             h_step(t);
    else if (t + 1 < Tv)  x_gemm(t + 1);
    if (t + 1 < Tv) { flag_barrier(flags, bid, ep); ++ep; }
  }
}

// ---------------- host launch ----------------
extern "C" void kernel_launch(void* const* d_in, const int* in_sizes, int n_in,
                              void* d_out, int out_size, void* d_ws, size_t ws_size,
                              hipStream_t stream) {
  const float* x    = (const float*)d_in[0];
  const float* w_ih = (const float*)d_in[1];
  const float* b_ih = (const float*)d_in[2];
  const float* w_hh = (const float*)d_in[3];
  const float* b_hh = (const float*)d_in[4];
  float* out = (float*)d_out;

  char* ws = (char*)d_ws;
  __hip_bfloat16* wbih = (__hip_bfloat16*)(ws);                              // 8 MB
  __hip_bfloat16* wbhh = (__hip_bfloat16*)(ws + (size_t)(8u << 20));         // 8 MB
  float*          bias = (float*)(ws + (size_t)(16u << 20));                 // 16 KB
  __hip_bfloat16* hbuf = (__hip_bfloat16*)(ws + (size_t)(16u << 20) + 65536);// 256 KB
  float*          xg   = (float*)(ws + (size_t)(16u << 20) + 65536 + 262144);// 2 MB
  unsigned*       flags= (unsigned*)(ws + (size_t)(20u << 20));              // 8 KB

  hipLaunchKernelGGL(prep, dim3(16384), dim3(256), 0, stream,
                     w_ih, w_hh, b_ih, b_hh, wbih, wbhh, bias, hbuf, flags);

  const unsigned ldsBytes = 131072u + 64u * 65u * 4u;  // 147712
  hipFuncSetAttribute((const void*)lstm_main,
                      hipFuncAttributeMaxDynamicSharedMemorySize, (int)ldsBytes);

  const float* xA = x;
  const __hip_bfloat16* wbihA = wbih;
  const __hip_bfloat16* wbhhA = wbhh;
  const float* biasA = bias;
  __hip_bfloat16* hbufA = hbuf;
  float* xgA = xg;
  float* outA = out;
  unsigned* flagsA = flags;
  void* args[8] = {(void*)&xA, (void*)&wbihA, (void*)&wbhhA, (void*)&biasA,
                   (void*)&hbufA, (void*)&xgA, (void*)&outA, (void*)&flagsA};
  hipLaunchCooperativeKernel((const void*)lstm_main, dim3(NBLK), dim3(256),
                             args, ldsBytes, stream);
}

// Round 4
// 6867.525 us; speedup vs baseline: 3.8168x; 1.5062x over previous
//
#include <hip/hip_runtime.h>
#include <hip/hip_bf16.h>

#define Bv 64
#define Tv 512
#define Iv 1024
#define Hv 1024
#define G4v 4096
#define NHB 64          // recurrent blocks
#define NXB 128         // producer blocks (2 per 64-col slice, row-split)
#define NBLK (NHB + NXB)
#define DEPTH 8         // xg ring depth (power of 2)
#define FSTR 16         // flag padding: 64B

typedef __attribute__((ext_vector_type(8))) short bf16x8;
typedef __attribute__((ext_vector_type(4))) float f32x4;

#define LOADC(p)    __hip_atomic_load((p), __ATOMIC_RELAXED, __HIP_MEMORY_SCOPE_AGENT)
#define STOREC(p,v) __hip_atomic_store((p), (v), __ATOMIC_RELAXED, __HIP_MEMORY_SCOPE_AGENT)

__device__ __forceinline__ float sigmoid_f(float v) { return 1.f / (1.f + __expf(-v)); }
__device__ __forceinline__ float tanh_f(float v) { return 1.f - 2.f / (__expf(2.f * v) + 1.f); }

// ---------------- prep: weights -> bf16, bias sum, zero h ping-pong + flags ----------------
__global__ void prep(const float* __restrict__ w_ih, const float* __restrict__ w_hh,
                     const float* __restrict__ b_ih, const float* __restrict__ b_hh,
                     __hip_bfloat16* __restrict__ wbih, __hip_bfloat16* __restrict__ wbhh,
                     float* __restrict__ bias, __hip_bfloat16* __restrict__ hbuf,
                     unsigned* __restrict__ hflag, unsigned* __restrict__ xflag) {
  unsigned i = blockIdx.x * 256u + threadIdx.x;   // grid covers exactly 4096*1024
  wbih[i] = __float2bfloat16(w_ih[i]);
  wbhh[i] = __float2bfloat16(w_hh[i]);
  if (i < (unsigned)G4v) bias[i] = b_ih[i] + b_hh[i];
  if (i < 2u * Bv * Hv) hbuf[i] = __float2bfloat16(0.f);
  if (i < (unsigned)(NHB * FSTR)) hflag[i] = 0u;
  if (i < (unsigned)(NXB * FSTR)) xflag[i] = 0u;
}

// ---------------- persistent dataflow LSTM (no grid barrier, no fences) ----------------
// blocks 0..63: h-blocks (own 16 h-cols = 64 gate-cols). blocks 64..191: x-blocks,
// j = bid-64, cb=j>>1 (gate-col slice), rh=j&1 (32-row half of batch).
// All cross-block traffic via agent-scope (sc1) loads/stores: writers write-through
// to LLC, readers bypass L1/L2 -> no acquire fence, L2 never invalidated.
// hflag[b] = steps completed by h-block b. xflag[j] = steps produced by x-block j.
// xg ring: DEPTH slots; h step t reads slot t&7 (needs xflag[2wg..2wg+1] >= t+1);
// x step t writes slot t&7 (needs all hflag >= t-DEPTH+1, i.e. slot consumed).
__global__ void __launch_bounds__(256, 1) lstm_main(
    const float* __restrict__ x,
    const __hip_bfloat16* __restrict__ wbih,
    const __hip_bfloat16* __restrict__ wbhh,
    const float* __restrict__ bias,
    __hip_bfloat16* __restrict__ hbuf,   // [2][B][H] bf16 ping-pong (sc1)
    float* __restrict__ xg,              // [DEPTH][B][4H] f32 ring (sc1)
    float* __restrict__ out,             // B*T*H + B*H + B*H
    unsigned* __restrict__ hflag,
    unsigned* __restrict__ xflag)
{
  extern __shared__ char lds[];
  float* gbuf = (float*)(lds + 131072);

  const int bid  = blockIdx.x;
  const bool is_h = (bid < NHB);
  const int tid  = threadIdx.x;
  const int lane = tid & 63;
  const int wave = tid >> 6;
  const int lrow = lane & 15;        // A row / B,D col within fragment
  const int lkg  = lane >> 4;        // 0..3
  const int lk   = lkg * 8;          // k offset within 32

  const int wg = is_h ? bid : ((bid - NHB) >> 1);   // gate-col slice 0..63
  const int rh = is_h ? 0 : ((bid - NHB) & 1);      // x row-half

  // ---- stage this block's 64x1024 weight slice into LDS (once, swizzled) ----
  {
    const __hip_bfloat16* wsrc = is_h ? wbhh : wbih;
    for (int c = tid; c < 8192; c += 256) {       // 8192 chunks of 16B = 128KB
      int n   = c >> 7;                           // local col 0..63
      int k16 = c & 127;                          // 16B chunk in k
      int gc  = ((n >> 4) << 10) + (wg << 4) + (n & 15);   // global gate row
      uint4 v = *(const uint4*)(wsrc + ((size_t)gc << 10) + (k16 << 3));
      unsigned byt = (unsigned)((n << 11) + (k16 << 4)) ^ ((unsigned)(n & 7) << 4);
      *(uint4*)(&lds[byt]) = v;
    }
  }
  __syncthreads();

  if (!is_h) {
    // ================= x-producer block: 32 rows x 64 gate-cols per step =================
    const int j  = bid - NHB;
    const int wr = wave & 1;       // 16-row tile within the 32-row half
    const int wc = wave >> 1;      // 32-col half
    const int arow = rh * 32 + wr * 16 + lrow;     // batch row for A loads
    const float* xa = x + (size_t)arow * (Tv * Iv) + lk;

    for (int t = 0; t < Tv; ++t) {
      if (t >= DEPTH) {            // slot t&7 must be consumed: all hflag >= t-DEPTH+1
        const unsigned tgt = (unsigned)(t - DEPTH + 1);
        for (;;) {
          unsigned hf = LOADC(&hflag[lane * FSTR]);
          if (__all(hf >= tgt)) break;
          __builtin_amdgcn_s_sleep(2);
        }
        asm volatile("" ::: "memory");
      }
      f32x4 acc[2];
      acc[0] = f32x4{0.f,0.f,0.f,0.f}; acc[1] = f32x4{0.f,0.f,0.f,0.f};
      const float* xt = xa + (size_t)t * Iv;
      #pragma unroll 4
      for (int ks = 0; ks < 32; ++ks) {
        int k0 = (ks << 5) + lk;
        float4 f0 = *(const float4*)(xt + (ks << 5));
        float4 f1 = *(const float4*)(xt + (ks << 5) + 4);
        union { __hip_bfloat16 e[8]; bf16x8 v; } u;
        u.e[0] = __float2bfloat16(f0.x); u.e[1] = __float2bfloat16(f0.y);
        u.e[2] = __float2bfloat16(f0.z); u.e[3] = __float2bfloat16(f0.w);
        u.e[4] = __float2bfloat16(f1.x); u.e[5] = __float2bfloat16(f1.y);
        u.e[6] = __float2bfloat16(f1.z); u.e[7] = __float2bfloat16(f1.w);
        bf16x8 b0, b1;
        {
          int n = wc * 32 + lrow;
          unsigned byt = (unsigned)((n << 11) + (k0 << 1)) ^ ((unsigned)(n & 7) << 4);
          b0 = *(const bf16x8*)(&lds[byt]);
          n += 16;
          byt = (unsigned)((n << 11) + (k0 << 1)) ^ ((unsigned)(n & 7) << 4);
          b1 = *(const bf16x8*)(&lds[byt]);
        }
        acc[0] = __builtin_amdgcn_mfma_f32_16x16x32_bf16(u.v, b0, acc[0], 0, 0, 0);
        acc[1] = __builtin_amdgcn_mfma_f32_16x16x32_bf16(u.v, b1, acc[1], 0, 0, 0);
      }
      float* dst = xg + (size_t)(t & (DEPTH - 1)) * (Bv * G4v);
      for (int nf = 0; nf < 2; ++nf) {
        int gc  = (wc * 2 + nf) * 1024 + (wg << 4) + lrow;   // global gate col
        int row = rh * 32 + wr * 16 + (lkg << 2);
        for (int r = 0; r < 4; ++r)
          STOREC(&dst[(size_t)(row + r) * G4v + gc], acc[nf][r]);
      }
      asm volatile("s_waitcnt vmcnt(0)" ::: "memory");
      __syncthreads();
      if (tid == 0) STOREC(&xflag[j * FSTR], (unsigned)(t + 1));
      __syncthreads();
    }
    return;
  }

  // ================= h-recurrent block: full h x 64 gate-cols per step =================
  const int eb  = tid >> 2;            // batch row 0..63 (elementwise)
  const int ec0 = (tid & 3) << 2;      // h-col offset base within 16
  float c_state[4] = {0.f, 0.f, 0.f, 0.f};
  float biasv[16];
  for (int g = 0; g < 4; ++g)
    for (int jj = 0; jj < 4; ++jj)
      biasv[g * 4 + jj] = bias[(g << 10) + (wg << 4) + ec0 + jj];

  const int ar = wave * 16 + lrow;     // A row this lane loads (16 rows per wave)

  for (int t = 0; t < Tv; ++t) {
    // ---- poll: all h-blocks done step t-1; my 2 xg producers done step t ----
    {
      const unsigned ht = (unsigned)t, xt = (unsigned)(t + 1);
      const unsigned* xf = &xflag[(2 * wg + (lane & 1)) * FSTR];
      for (;;) {
        unsigned hf = LOADC(&hflag[lane * FSTR]);
        unsigned xv = LOADC(xf);
        if (__all(hf >= ht && xv >= xt)) break;
        __builtin_amdgcn_s_sleep(2);
      }
      asm volatile("" ::: "memory");
    }
    // ---- xg slice -> registers (sc1 loads, overlap with GEMM) ----
    float xgv[16];
    {
      const unsigned long long* xq = (const unsigned long long*)
          (xg + (size_t)(t & (DEPTH - 1)) * (Bv * G4v) + (size_t)eb * G4v + (wg << 4) + ec0);
      #pragma unroll
      for (int g = 0; g < 4; ++g) {
        union { unsigned long long q[2]; float f[4]; } ux;
        ux.q[0] = LOADC(xq + g * 512);
        ux.q[1] = LOADC(xq + g * 512 + 1);
        xgv[g * 4 + 0] = ux.f[0]; xgv[g * 4 + 1] = ux.f[1];
        xgv[g * 4 + 2] = ux.f[2]; xgv[g * 4 + 3] = ux.f[3];
      }
    }
    // ---- h GEMM: A = h_{t} (sc1 8B loads from LLC), B = LDS weights ----
    const __hip_bfloat16* hp = hbuf + (size_t)((t + 1) & 1) * (Bv * Hv);
    const unsigned long long* hq = (const unsigned long long*)hp + (size_t)ar * 256 + lkg * 2;
    f32x4 acc[4];
    for (int nf = 0; nf < 4; ++nf) acc[nf] = f32x4{0.f,0.f,0.f,0.f};
    #pragma unroll 8
    for (int ks = 0; ks < 32; ++ks) {
      int k0 = (ks << 5) + lk;
      union { unsigned long long q[2]; bf16x8 v; } ua;
      ua.q[0] = LOADC(hq + ks * 8);
      ua.q[1] = LOADC(hq + ks * 8 + 1);
      #pragma unroll
      for (int nf = 0; nf < 4; ++nf) {
        int n = nf * 16 + lrow;
        unsigned byt = (unsigned)((n << 11) + (k0 << 1)) ^ ((unsigned)(n & 7) << 4);
        bf16x8 b = *(const bf16x8*)(&lds[byt]);
        acc[nf] = __builtin_amdgcn_mfma_f32_16x16x32_bf16(ua.v, b, acc[nf], 0, 0, 0);
      }
    }
    // ---- exchange gates through LDS ----
    #pragma unroll
    for (int nf = 0; nf < 4; ++nf)
      for (int r = 0; r < 4; ++r)
        gbuf[(wave * 16 + (lkg << 2) + r) * 65 + nf * 16 + lrow] = acc[nf][r];
    __syncthreads();
    float hv[4];
    #pragma unroll
    for (int jj = 0; jj < 4; ++jj) {
      int cc = ec0 + jj;
      float g0 = gbuf[eb * 65 +      cc] + xgv[0 + jj]  + biasv[0 + jj];
      float g1 = gbuf[eb * 65 + 16 + cc] + xgv[4 + jj]  + biasv[4 + jj];
      float g2 = gbuf[eb * 65 + 32 + cc] + xgv[8 + jj]  + biasv[8 + jj];
      float g3 = gbuf[eb * 65 + 48 + cc] + xgv[12 + jj] + biasv[12 + jj];
      float ig = sigmoid_f(g0);
      float fg = sigmoid_f(g1);
      float gg = tanh_f(g2);
      float og = sigmoid_f(g3);
      float cv = fg * c_state[jj] + ig * gg;
      c_state[jj] = cv;
      hv[jj] = og * tanh_f(cv);
    }
    // publish h slice (one 8B sc1 store) + out (nontemporal, keeps L2 clean)
    __hip_bfloat16* hw = hbuf + (size_t)(t & 1) * (Bv * Hv) + ((size_t)eb << 10) + (wg << 4) + ec0;
    union { __hip_bfloat16 h[4]; unsigned long long q; } hu;
    for (int jj = 0; jj < 4; ++jj) hu.h[jj] = __float2bfloat16(hv[jj]);
    STOREC((unsigned long long*)hw, hu.q);
    float* ow = out + (size_t)eb * (Tv * Hv) + ((size_t)t << 10) + (wg << 4) + ec0;
    f32x4 ov = {hv[0], hv[1], hv[2], hv[3]};
    __builtin_nontemporal_store(ov, (f32x4*)ow);
    if (t == Tv - 1) {
      float* hn = out + (size_t)Bv * Tv * Hv + ((size_t)eb << 10) + (wg << 4) + ec0;
      float* cn = hn + (size_t)Bv * Hv;
      for (int jj = 0; jj < 4; ++jj) { hn[jj] = hv[jj]; cn[jj] = c_state[jj]; }
    }
    asm volatile("s_waitcnt vmcnt(0)" ::: "memory");
    __syncthreads();                    // all waves drained (also guards gbuf reuse)
    if (tid == 0) STOREC(&hflag[wg * FSTR], (unsigned)(t + 1));
    __syncthreads();
  }
}

// ---------------- host launch ----------------
extern "C" void kernel_launch(void* const* d_in, const int* in_sizes, int n_in,
                              void* d_out, int out_size, void* d_ws, size_t ws_size,
                              hipStream_t stream) {
  const float* x    = (const float*)d_in[0];
  const float* w_ih = (const float*)d_in[1];
  const float* b_ih = (const float*)d_in[2];
  const float* w_hh = (const float*)d_in[3];
  const float* b_hh = (const float*)d_in[4];
  float* out = (float*)d_out;

  char* ws = (char*)d_ws;
  __hip_bfloat16* wbih = (__hip_bfloat16*)(ws);                        // 8 MB
  __hip_bfloat16* wbhh = (__hip_bfloat16*)(ws + ((size_t)8 << 20));    // 8 MB
  float*          bias = (float*)(ws + ((size_t)16 << 20));            // 16 KB
  __hip_bfloat16* hbuf = (__hip_bfloat16*)(ws + ((size_t)16 << 20) + 65536); // 256 KB
  float*          xg   = (float*)(ws + ((size_t)18 << 20));            // 8 MB ring
  unsigned*       hflag= (unsigned*)(ws + ((size_t)26 << 20));         // 4 KB
  unsigned*       xflag= (unsigned*)(ws + ((size_t)26 << 20) + 8192);  // 8 KB

  hipLaunchKernelGGL(prep, dim3(16384), dim3(256), 0, stream,
                     w_ih, w_hh, b_ih, b_hh, wbih, wbhh, bias, hbuf, hflag, xflag);

  const unsigned ldsBytes = 131072u + 64u * 65u * 4u;  // 147712
  hipFuncSetAttribute((const void*)lstm_main,
                      hipFuncAttributeMaxDynamicSharedMemorySize, (int)ldsBytes);

  const float* xA = x;
  const __hip_bfloat16* wbihA = wbih;
  const __hip_bfloat16* wbhhA = wbhh;
  const float* biasA = bias;
  __hip_bfloat16* hbufA = hbuf;
  float* xgA = xg;
  float* outA = out;
  unsigned* hflagA = hflag;
  unsigned* xflagA = xflag;
  void* args[9] = {(void*)&xA, (void*)&wbihA, (void*)&wbhhA, (void*)&biasA,
                   (void*)&hbufA, (void*)&xgA, (void*)&outA, (void*)&hflagA, (void*)&xflagA};
  hipLaunchCooperativeKernel((const void*)lstm_main, dim3(NBLK), dim3(256),
                             args, ldsBytes, stream);
}

// Round 7
// 5362.674 us; speedup vs baseline: 4.8879x; 1.2806x over previous
//
#include <hip/hip_runtime.h>
#include <hip/hip_bf16.h>

#define Bv 64
#define Tv 512
#define Iv 1024
#define Hv 1024
#define G4v 4096
#define NHB 64          // recurrent blocks
#define NXB 128         // producer blocks (2 per 64-col slice, row-split)
#define NBLK (NHB + NXB)
#define DEPTH 8         // xg ring depth (power of 2)
#define FSTR 16         // flag padding: 64B

typedef __attribute__((ext_vector_type(8))) short bf16x8;
typedef __attribute__((ext_vector_type(4))) float f32x4;

#define LOADC(p)    __hip_atomic_load((p), __ATOMIC_RELAXED, __HIP_MEMORY_SCOPE_AGENT)
#define STOREC(p,v) __hip_atomic_store((p), (v), __ATOMIC_RELAXED, __HIP_MEMORY_SCOPE_AGENT)

__device__ __forceinline__ float sigmoid_f(float v) { return 1.f / (1.f + __expf(-v)); }
__device__ __forceinline__ float tanh_f(float v) { return 1.f - 2.f / (__expf(2.f * v) + 1.f); }

// ---------------- prep: weights -> bf16, bias sum, zero h ping-pong + flags ----------------
__global__ void prep(const float* __restrict__ w_ih, const float* __restrict__ w_hh,
                     const float* __restrict__ b_ih, const float* __restrict__ b_hh,
                     __hip_bfloat16* __restrict__ wbih, __hip_bfloat16* __restrict__ wbhh,
                     float* __restrict__ bias, __hip_bfloat16* __restrict__ hbuf,
                     unsigned* __restrict__ hflag, unsigned* __restrict__ xflag) {
  unsigned i = blockIdx.x * 256u + threadIdx.x;   // grid covers exactly 4096*1024
  wbih[i] = __float2bfloat16(w_ih[i]);
  wbhh[i] = __float2bfloat16(w_hh[i]);
  if (i < (unsigned)G4v) bias[i] = b_ih[i] + b_hh[i];
  if (i < 2u * Bv * Hv) hbuf[i] = __float2bfloat16(0.f);
  if (i < (unsigned)(NHB * FSTR)) hflag[i] = 0u;
  if (i < (unsigned)(NXB * FSTR)) xflag[i] = 0u;
}

// A-chunk pipeline: chunk = 4 k-steps = 8 x 8B sc1 loads into a NAMED register
// buffer (16 VGPRs each; static indices only). 2 buffers ping-pong.
#define LOAD4(buf, cc)                                                  \
  _Pragma("unroll")                                                     \
  for (int j = 0; j < 4; ++j) {                                         \
    buf[2 * j]     = LOADC(hq + ((cc) * 4 + j) * 8);                    \
    buf[2 * j + 1] = LOADC(hq + ((cc) * 4 + j) * 8 + 1);                \
  }
#define MFMA4(buf, cc)                                                  \
  _Pragma("unroll")                                                     \
  for (int j = 0; j < 4; ++j) {                                         \
    int k0 = (((cc) * 4 + j) << 5) + lk;                                \
    union { unsigned long long q[2]; bf16x8 v; } ua;                    \
    ua.q[0] = buf[2 * j]; ua.q[1] = buf[2 * j + 1];                     \
    _Pragma("unroll")                                                   \
    for (int nf = 0; nf < 4; ++nf) {                                    \
      int n = nf * 16 + lrow;                                           \
      unsigned byt = (unsigned)((n << 11) + (k0 << 1)) ^ ((unsigned)(n & 7) << 4); \
      bf16x8 b = *(const bf16x8*)(&lds[byt]);                           \
      acc[nf] = __builtin_amdgcn_mfma_f32_16x16x32_bf16(ua.v, b, acc[nf], 0, 0, 0); \
    }                                                                   \
  }

// ---------------- persistent dataflow LSTM (no grid barrier, no fences) ----------------
// blocks 0..63: h-blocks (own 16 h-cols = 64 gate-cols). blocks 64..191: x-blocks.
// All cross-block traffic via agent-scope (sc1) loads/stores: writers write-through
// to LLC, readers bypass L1/L2 -> no acquire fence, L2 never invalidated.
// hflag[b] = steps completed by h-block b. xflag[j] = steps produced by x-block j.
// xg ring: DEPTH slots; h step t reads slot t&7 (needs xflag[2wg..2wg+1] >= t+1);
// x step t writes slot t&7 (needs all hflag >= t-DEPTH+1, i.e. slot consumed).
__global__ void __launch_bounds__(256, 1) lstm_main(
    const float* __restrict__ x,
    const __hip_bfloat16* __restrict__ wbih,
    const __hip_bfloat16* __restrict__ wbhh,
    const float* __restrict__ bias,
    __hip_bfloat16* __restrict__ hbuf,   // [2][B][H] bf16 ping-pong (sc1)
    float* __restrict__ xg,              // [DEPTH][B][4H] f32 ring (sc1)
    float* __restrict__ out,             // B*T*H + B*H + B*H
    unsigned* __restrict__ hflag,
    unsigned* __restrict__ xflag)
{
  extern __shared__ char lds[];
  float* gbuf = (float*)(lds + 131072);

  const int bid  = blockIdx.x;
  const bool is_h = (bid < NHB);
  const int tid  = threadIdx.x;
  const int lane = tid & 63;
  const int wave = tid >> 6;
  const int lrow = lane & 15;        // A row / B,D col within fragment
  const int lkg  = lane >> 4;        // 0..3
  const int lk   = lkg * 8;          // k offset within 32

  const int wg = is_h ? bid : ((bid - NHB) >> 1);   // gate-col slice 0..63
  const int rh = is_h ? 0 : ((bid - NHB) & 1);      // x row-half

  // ---- stage this block's 64x1024 weight slice into LDS (once, swizzled) ----
  {
    const __hip_bfloat16* wsrc = is_h ? wbhh : wbih;
    for (int c = tid; c < 8192; c += 256) {       // 8192 chunks of 16B = 128KB
      int n   = c >> 7;                           // local col 0..63
      int k16 = c & 127;                          // 16B chunk in k
      int gc  = ((n >> 4) << 10) + (wg << 4) + (n & 15);   // global gate row
      uint4 v = *(const uint4*)(wsrc + ((size_t)gc << 10) + (k16 << 3));
      unsigned byt = (unsigned)((n << 11) + (k16 << 4)) ^ ((unsigned)(n & 7) << 4);
      *(uint4*)(&lds[byt]) = v;
    }
  }
  __syncthreads();

  if (!is_h) {
    // ================= x-producer block: 32 rows x 64 gate-cols per step =================
    const int j  = bid - NHB;
    const int wr = wave & 1;       // 16-row tile within the 32-row half
    const int wc = wave >> 1;      // 32-col half
    const int arow = rh * 32 + wr * 16 + lrow;     // batch row for A loads
    const float* xa = x + (size_t)arow * (Tv * Iv) + lk;

    for (int t = 0; t < Tv; ++t) {
      if (t >= DEPTH) {            // slot t&7 must be consumed: all hflag >= t-DEPTH+1
        const unsigned tgt = (unsigned)(t - DEPTH + 1);
        for (;;) {
          unsigned hf = LOADC(&hflag[lane * FSTR]);
          if (__all(hf >= tgt)) break;
          __builtin_amdgcn_s_sleep(2);
        }
        asm volatile("" ::: "memory");
      }
      f32x4 acc[2];
      acc[0] = f32x4{0.f,0.f,0.f,0.f}; acc[1] = f32x4{0.f,0.f,0.f,0.f};
      const float* xt = xa + (size_t)t * Iv;
      #pragma unroll 4
      for (int ks = 0; ks < 32; ++ks) {
        int k0 = (ks << 5) + lk;
        float4 f0 = *(const float4*)(xt + (ks << 5));
        float4 f1 = *(const float4*)(xt + (ks << 5) + 4);
        union { __hip_bfloat16 e[8]; bf16x8 v; } u;
        u.e[0] = __float2bfloat16(f0.x); u.e[1] = __float2bfloat16(f0.y);
        u.e[2] = __float2bfloat16(f0.z); u.e[3] = __float2bfloat16(f0.w);
        u.e[4] = __float2bfloat16(f1.x); u.e[5] = __float2bfloat16(f1.y);
        u.e[6] = __float2bfloat16(f1.z); u.e[7] = __float2bfloat16(f1.w);
        bf16x8 b0, b1;
        {
          int n = wc * 32 + lrow;
          unsigned byt = (unsigned)((n << 11) + (k0 << 1)) ^ ((unsigned)(n & 7) << 4);
          b0 = *(const bf16x8*)(&lds[byt]);
          n += 16;
          byt = (unsigned)((n << 11) + (k0 << 1)) ^ ((unsigned)(n & 7) << 4);
          b1 = *(const bf16x8*)(&lds[byt]);
        }
        acc[0] = __builtin_amdgcn_mfma_f32_16x16x32_bf16(u.v, b0, acc[0], 0, 0, 0);
        acc[1] = __builtin_amdgcn_mfma_f32_16x16x32_bf16(u.v, b1, acc[1], 0, 0, 0);
      }
      float* dst = xg + (size_t)(t & (DEPTH - 1)) * (Bv * G4v);
      for (int nf = 0; nf < 2; ++nf) {
        int gc  = (wc * 2 + nf) * 1024 + (wg << 4) + lrow;   // global gate col
        int row = rh * 32 + wr * 16 + (lkg << 2);
        for (int r = 0; r < 4; ++r)
          STOREC(&dst[(size_t)(row + r) * G4v + gc], acc[nf][r]);
      }
      asm volatile("s_waitcnt vmcnt(0)" ::: "memory");
      __syncthreads();
      if (tid == 0) STOREC(&xflag[j * FSTR], (unsigned)(t + 1));
      __syncthreads();
    }
    return;
  }

  // ================= h-recurrent block: full h x 64 gate-cols per step =================
  const int eb  = tid >> 2;            // batch row 0..63 (elementwise)
  const int ec0 = (tid & 3) << 2;      // h-col offset base within 16
  float c_state[4] = {0.f, 0.f, 0.f, 0.f};
  float biasv[16];
  for (int g = 0; g < 4; ++g)
    for (int jj = 0; jj < 4; ++jj)
      biasv[g * 4 + jj] = bias[(g << 10) + (wg << 4) + ec0 + jj];

  const int ar = wave * 16 + lrow;     // A row this lane loads (16 rows per wave)

  for (int t = 0; t < Tv; ++t) {
    // ---- poll: all h-blocks done step t-1; my 2 xg producers done step t ----
    {
      const unsigned ht = (unsigned)t, xtg = (unsigned)(t + 1);
      const unsigned* xf = &xflag[(2 * wg + (lane & 1)) * FSTR];
      for (;;) {
        unsigned hf = LOADC(&hflag[lane * FSTR]);
        unsigned xv = LOADC(xf);
        if (__all(hf >= ht && xv >= xtg)) break;
        __builtin_amdgcn_s_sleep(2);
      }
      asm volatile("" ::: "memory");
    }
    // ---- xg slice -> registers (sc1; in flight alongside the A chunks) ----
    float xgv[16];
    {
      const unsigned long long* xq = (const unsigned long long*)
          (xg + (size_t)(t & (DEPTH - 1)) * (Bv * G4v) + (size_t)eb * G4v + (wg << 4) + ec0);
      #pragma unroll
      for (int g = 0; g < 4; ++g) {
        union { unsigned long long q[2]; float f[4]; } ux;
        ux.q[0] = LOADC(xq + g * 512);
        ux.q[1] = LOADC(xq + g * 512 + 1);
        xgv[g * 4 + 0] = ux.f[0]; xgv[g * 4 + 1] = ux.f[1];
        xgv[g * 4 + 2] = ux.f[2]; xgv[g * 4 + 3] = ux.f[3];
      }
    }
    // ---- h GEMM: 2-buffer x 4-kstep A pipeline (8x8B sc1 loads per chunk) ----
    const __hip_bfloat16* hp = hbuf + (size_t)((t + 1) & 1) * (Bv * Hv);
    const unsigned long long* hq = (const unsigned long long*)hp + (size_t)ar * 256 + lkg * 2;
    f32x4 acc[4];
    for (int nf = 0; nf < 4; ++nf) acc[nf] = f32x4{0.f,0.f,0.f,0.f};
    {
      unsigned long long aqA[8], aqB[8];
      LOAD4(aqA, 0)
      LOAD4(aqB, 1)
      MFMA4(aqA, 0) LOAD4(aqA, 2)
      MFMA4(aqB, 1) LOAD4(aqB, 3)
      MFMA4(aqA, 2) LOAD4(aqA, 4)
      MFMA4(aqB, 3) LOAD4(aqB, 5)
      MFMA4(aqA, 4) LOAD4(aqA, 6)
      MFMA4(aqB, 5) LOAD4(aqB, 7)
      MFMA4(aqA, 6)
      MFMA4(aqB, 7)
    }
    // ---- exchange gates through LDS ----
    #pragma unroll
    for (int nf = 0; nf < 4; ++nf)
      for (int r = 0; r < 4; ++r)
        gbuf[(wave * 16 + (lkg << 2) + r) * 65 + nf * 16 + lrow] = acc[nf][r];
    __syncthreads();
    float hv[4];
    #pragma unroll
    for (int jj = 0; jj < 4; ++jj) {
      int cc = ec0 + jj;
      float g0 = gbuf[eb * 65 +      cc] + xgv[0 + jj]  + biasv[0 + jj];
      float g1 = gbuf[eb * 65 + 16 + cc] + xgv[4 + jj]  + biasv[4 + jj];
      float g2 = gbuf[eb * 65 + 32 + cc] + xgv[8 + jj]  + biasv[8 + jj];
      float g3 = gbuf[eb * 65 + 48 + cc] + xgv[12 + jj] + biasv[12 + jj];
      float ig = sigmoid_f(g0);
      float fg = sigmoid_f(g1);
      float gg = tanh_f(g2);
      float og = sigmoid_f(g3);
      float cv = fg * c_state[jj] + ig * gg;
      c_state[jj] = cv;
      hv[jj] = og * tanh_f(cv);
    }
    // publish h slice (one 8B sc1 store); drain covers ONLY this store
    __hip_bfloat16* hw = hbuf + (size_t)(t & 1) * (Bv * Hv) + ((size_t)eb << 10) + (wg << 4) + ec0;
    union { __hip_bfloat16 h[4]; unsigned long long q; } hu;
    for (int jj = 0; jj < 4; ++jj) hu.h[jj] = __float2bfloat16(hv[jj]);
    STOREC((unsigned long long*)hw, hu.q);
    asm volatile("s_waitcnt vmcnt(0)" ::: "memory");
    __syncthreads();                    // all waves' h stores at LLC
    if (tid == 0) STOREC(&hflag[wg * FSTR], (unsigned)(t + 1));
    // ---- out stores AFTER flag publish: HBM ack off the critical path ----
    float* ow = out + (size_t)eb * (Tv * Hv) + ((size_t)t << 10) + (wg << 4) + ec0;
    f32x4 ov = {hv[0], hv[1], hv[2], hv[3]};
    __builtin_nontemporal_store(ov, (f32x4*)ow);
    if (t == Tv - 1) {
      float* hn = out + (size_t)Bv * Tv * Hv + ((size_t)eb << 10) + (wg << 4) + ec0;
      float* cn = hn + (size_t)Bv * Hv;
      for (int jj = 0; jj < 4; ++jj) { hn[jj] = hv[jj]; cn[jj] = c_state[jj]; }
    }
    __syncthreads();
  }
}

// ---------------- host launch ----------------
extern "C" void kernel_launch(void* const* d_in, const int* in_sizes, int n_in,
                              void* d_out, int out_size, void* d_ws, size_t ws_size,
                              hipStream_t stream) {
  const float* x    = (const float*)d_in[0];
  const float* w_ih = (const float*)d_in[1];
  const float* b_ih = (const float*)d_in[2];
  const float* w_hh = (const float*)d_in[3];
  const float* b_hh = (const float*)d_in[4];
  float* out = (float*)d_out;

  char* ws = (char*)d_ws;
  __hip_bfloat16* wbih = (__hip_bfloat16*)(ws);                        // 8 MB
  __hip_bfloat16* wbhh = (__hip_bfloat16*)(ws + ((size_t)8 << 20));    // 8 MB
  float*          bias = (float*)(ws + ((size_t)16 << 20));            // 16 KB
  __hip_bfloat16* hbuf = (__hip_bfloat16*)(ws + ((size_t)16 << 20) + 65536); // 256 KB
  float*          xg   = (float*)(ws + ((size_t)18 << 20));            // 8 MB ring
  unsigned*       hflag= (unsigned*)(ws + ((size_t)26 << 20));         // 4 KB
  unsigned*       xflag= (unsigned*)(ws + ((size_t)26 << 20) + 8192);  // 8 KB

  hipLaunchKernelGGL(prep, dim3(16384), dim3(256), 0, stream,
                     w_ih, w_hh, b_ih, b_hh, wbih, wbhh, bias, hbuf, hflag, xflag);

  const unsigned ldsBytes = 131072u + 64u * 65u * 4u;  // 147712
  hipFuncSetAttribute((const void*)lstm_main,
                      hipFuncAttributeMaxDynamicSharedMemorySize, (int)ldsBytes);

  const float* xA = x;
  const __hip_bfloat16* wbihA = wbih;
  const __hip_bfloat16* wbhhA = wbhh;
  const float* biasA = bias;
  __hip_bfloat16* hbufA = hbuf;
  float* xgA = xg;
  float* outA = out;
  unsigned* hflagA = hflag;
  unsigned* xflagA = xflag;
  void* args[9] = {(void*)&xA, (void*)&wbihA, (void*)&wbhhA, (void*)&biasA,
                   (void*)&hbufA, (void*)&xgA, (void*)&outA, (void*)&hflagA, (void*)&xflagA};

  // Cooperative launch guarantees co-residency, but its validation can reject
  // silently (R5/R6 zero-output signature). Our sync protocol uses only our own
  // flags (no cg::grid.sync), and 147712B LDS forces 1 block/CU so 192 blocks
  // co-reside under a plain launch too. Fall back if coop launch errors.
  hipError_t lerr = hipLaunchCooperativeKernel((const void*)lstm_main, dim3(NBLK),
                                               dim3(256), args, ldsBytes, stream);
  if (lerr != hipSuccess) {
    (void)hipGetLastError();   // clear sticky error, then plain launch
    hipLaunchKernelGGL(lstm_main, dim3(NBLK), dim3(256), ldsBytes, stream,
                       xA, wbihA, wbhhA, biasA, hbufA, xgA, outA, hflagA, xflagA);
  }
}